// Round 8
// baseline (436.759 us; speedup 1.0000x reference)
//
#include <hip/hip_runtime.h>
#include <hip/hip_bf16.h>

// Problem constants
#define BB    8
#define NBB   1024
#define KK    9
#define CC    32
#define CMM   128
#define NTOT  (BB*NBB)        // 8192
#define MM    (NBB*KK)        // 9216 per batch
#define NEG   0.01f
#define EPS   1e-5f
#define SQL2  1.6986436f      /* sqrt(2*log2(e)); E = -((s*dx)^2 + (s*dy)^2) */

// Workspace layout (floats)
#define OFF_CWT   0
#define SZ_CWT    (BB*CC*MM/2)            // bf16 in float-slots: 1179648
#define OFF_QPX   (OFF_CWT + SZ_CWT)
#define OFF_QPY   (OFF_QPX + BB*MM)
#define OFF_X0    (OFF_QPY + BB*MM)
#define OFF_X     (OFF_X0 + NTOT*CC)
#define OFF_H0    (OFF_X + NTOT*CC)
#define OFF_ST    (OFF_H0 + NTOT*CMM)     // stats: s1[64] then s2[256]

typedef __attribute__((ext_vector_type(8))) short short8;
typedef __attribute__((ext_vector_type(4))) float f32x4;
typedef __attribute__((ext_vector_type(2))) float f32x2;

static __device__ __forceinline__ unsigned short f2bf_rne(float f) {
    __hip_bfloat16 h = __float2bfloat16(f);
    return *reinterpret_cast<unsigned short*>(&h);
}

// ---------------------------------------------------------------------------
// Grid barrier (r2-proven protocol): generation counter, self-resetting
// across graph replays. Producer: __threadfence (device release) before
// arrival; consumer: acquire load + __threadfence after.
// ---------------------------------------------------------------------------
__device__ unsigned g_cnt[2];
__device__ unsigned g_gen[2];

static __device__ __forceinline__ void grid_sync(int i, unsigned nblk) {
    __threadfence();
    __syncthreads();
    if (threadIdx.x == 0) {
        unsigned g = __hip_atomic_load(&g_gen[i], __ATOMIC_RELAXED, __HIP_MEMORY_SCOPE_AGENT);
        unsigned a = __hip_atomic_fetch_add(&g_cnt[i], 1u, __ATOMIC_ACQ_REL, __HIP_MEMORY_SCOPE_AGENT);
        if (a == nblk - 1u) {
            __hip_atomic_store(&g_cnt[i], 0u, __ATOMIC_RELAXED, __HIP_MEMORY_SCOPE_AGENT);
            __hip_atomic_store(&g_gen[i], g + 1u, __ATOMIC_RELEASE, __HIP_MEMORY_SCOPE_AGENT);
        } else {
            while (__hip_atomic_load(&g_gen[i], __ATOMIC_ACQUIRE, __HIP_MEMORY_SCOPE_AGENT) == g)
                __builtin_amdgcn_s_sleep(2);
        }
    }
    __syncthreads();
    __threadfence();
}

// ---------------------------------------------------------------------------
// cwT layout: A-fragment tiles. Element (b, m, c) lives at short offset
//   b*CC*MM + (m>>5)*1024 + c*32 + (m&31)
// -> a wave's MFMA A-frag load is a contiguous 2 KB block (coalesced).
// ---------------------------------------------------------------------------

// 3-buffer rotating prefetch macros (sample phase)
#define LOADSET(A0,A1,XX0,XX1,YY0,YY1,it) do { \
    int _i = (it) < 18 ? (it) : 17; \
    int _m = wvm + _i*32; \
    int _a = _i*1024; \
    A0 = *(const short8*)&cab[_a]; \
    A1 = *(const short8*)&cab[_a + 512]; \
    XX0 = *(const f32x4*)&qx[_m]; XX1 = *(const f32x4*)&qx[_m + 4]; \
    YY0 = *(const f32x4*)&qy[_m]; YY1 = *(const f32x4*)&qy[_m + 4]; \
} while (0)

#define COMPUTE(A0,A1,XX0,XX1,YY0,YY1) do { \
    _Pragma("unroll") \
    for (int nt = 0; nt < 2; ++nt) { \
        f32x2 PX = {px[nt], px[nt]}; \
        f32x2 PY = {py[nt], py[nt]}; \
        f32x2 dx0 = (f32x2){XX0.x, XX0.y} - PX; \
        f32x2 dy0 = (f32x2){YY0.x, YY0.y} - PY; \
        f32x2 t0 = dx0*dx0; t0 = dy0*dy0 + t0; \
        f32x2 dx1 = (f32x2){XX0.z, XX0.w} - PX; \
        f32x2 dy1 = (f32x2){YY0.z, YY0.w} - PY; \
        f32x2 t1 = dx1*dx1; t1 = dy1*dy1 + t1; \
        f32x2 dx2 = (f32x2){XX1.x, XX1.y} - PX; \
        f32x2 dy2 = (f32x2){YY1.x, YY1.y} - PY; \
        f32x2 t2 = dx2*dx2; t2 = dy2*dy2 + t2; \
        f32x2 dx3 = (f32x2){XX1.z, XX1.w} - PX; \
        f32x2 dy3 = (f32x2){YY1.z, YY1.w} - PY; \
        f32x2 t3 = dx3*dx3; t3 = dy3*dy3 + t3; \
        float e0 = __builtin_amdgcn_exp2f(-t0.x); \
        float e1 = __builtin_amdgcn_exp2f(-t0.y); \
        float e2 = __builtin_amdgcn_exp2f(-t1.x); \
        float e3 = __builtin_amdgcn_exp2f(-t1.y); \
        float e4 = __builtin_amdgcn_exp2f(-t2.x); \
        float e5 = __builtin_amdgcn_exp2f(-t2.y); \
        float e6 = __builtin_amdgcn_exp2f(-t3.x); \
        float e7 = __builtin_amdgcn_exp2f(-t3.y); \
        union { unsigned int u[4]; short8 s; } bf; \
        bf.u[0] = __builtin_amdgcn_perm(__float_as_uint(e1), __float_as_uint(e0), 0x07060302u); \
        bf.u[1] = __builtin_amdgcn_perm(__float_as_uint(e3), __float_as_uint(e2), 0x07060302u); \
        bf.u[2] = __builtin_amdgcn_perm(__float_as_uint(e5), __float_as_uint(e4), 0x07060302u); \
        bf.u[3] = __builtin_amdgcn_perm(__float_as_uint(e7), __float_as_uint(e6), 0x07060302u); \
        acc[nt][0] = __builtin_amdgcn_mfma_f32_16x16x32_bf16(A0, bf.s, acc[nt][0], 0, 0, 0); \
        acc[nt][1] = __builtin_amdgcn_mfma_f32_16x16x32_bf16(A1, bf.s, acc[nt][1], 0, 0, 0); \
    } \
} while (0)

// ---------------------------------------------------------------------------
// k_cs: convw (+prep) then sample, fused with ONE grid barrier.
// grid = 256 x 1024 (16 waves, 4 waves/SIMD, 1 block/CU by VGPR+LDS).
// Phase A: prep (single pass over grid), kw->LDS staging (all waves),
//          convw MFMA on waves 0..3 (ntile=wv&1, c-half=wv>>1), contiguous
//          tiled cwT writeout. Same-XCD mapping (b=blk&7) keeps cwT L2-hot.
// Phase B: r7 sample verbatim: 32 n/block, 16-way m-split, 3-buffer
//          prefetch, LDS reduce, leaky, x0 + s1 atomics.
// ---------------------------------------------------------------------------
__global__ __launch_bounds__(1024, 4) void k_cs(const float* __restrict__ pos,
                                                const float* __restrict__ kpos,
                                                const float* __restrict__ w,
                                                const float* __restrict__ kw,
                                                float* __restrict__ qpx,
                                                float* __restrict__ qpy,
                                                const short* __restrict__ cwTr,
                                                short* __restrict__ cwT,
                                                float* __restrict__ x0,
                                                float* __restrict__ stats) {
    __shared__ float red[16*32*36];   // 72 KB: phase B [wv][nloc][c] pad 36
    __shared__ float sstat[64];
    // phase A aliases into red (36 KB used)
    unsigned short* kwl  = (unsigned short*)red;          // 18 KB [k][c][cp]
    unsigned short* tile = (unsigned short*)red + 9216;   // 18 KB [mchunk][c][m%32]

    int t = threadIdx.x;
    int l = t & 63, wv = t >> 6;
    int blk = blockIdx.x;
    int b = blk & 7, nblk = blk >> 3;          // XCD-aligned batch; 32-n tile
    int lane15 = l & 15, quad = l >> 4;
    if (t < 64) sstat[t] = 0.f;

    // ======================= phase A: prep + convw =======================
    if (blk == 0 && t < 320) stats[t] = 0.f;
    {
        int gid = blk*1024 + t;                // single pass: 262144 >= 73728
        if (gid < BB*MM) {
            int bb = gid / MM;
            int m = gid - bb*MM;
            int np = m / 9, k9 = m - np*9;
            float qxv = pos[((size_t)(bb*NBB + np))*2 + 0] + kpos[k9*2 + 0];
            float qyv = pos[((size_t)(bb*NBB + np))*2 + 1] + kpos[k9*2 + 1];
            qpx[gid] = SQL2*qxv;
            qpy[gid] = SQL2*qyv;
        }
    }
    // stage kw -> LDS bf16 transposed [k][c][cp]
    for (int u = t; u < KK*CC*CC/4; u += 1024) {
        int flat = u*4;
        int row = flat >> 5;
        int c0 = flat & 31;
        int kk = row >> 5, cp = row & 31;
        f32x4 v = *(const f32x4*)&kw[flat];
        kwl[(kk*CC + c0+0)*CC + cp] = f2bf_rne(v.x);
        kwl[(kk*CC + c0+1)*CC + cp] = f2bf_rne(v.y);
        kwl[(kk*CC + c0+2)*CC + cp] = f2bf_rne(v.z);
        kwl[(kk*CC + c0+3)*CC + cp] = f2bf_rne(v.w);
    }
    // B-frag (waves 0..3 use; others harmless dup)
    {
        int n = b*NBB + nblk*32 + (wv & 1)*16 + lane15;
        f32x4 w0 = *(const f32x4*)&w[(size_t)n*CC + quad*8];
        f32x4 w1 = *(const f32x4*)&w[(size_t)n*CC + quad*8 + 4];
        union { unsigned short us[8]; short8 s; } bfr;
        bfr.us[0] = f2bf_rne(w0.x); bfr.us[1] = f2bf_rne(w0.y);
        bfr.us[2] = f2bf_rne(w0.z); bfr.us[3] = f2bf_rne(w0.w);
        bfr.us[4] = f2bf_rne(w1.x); bfr.us[5] = f2bf_rne(w1.y);
        bfr.us[6] = f2bf_rne(w1.z); bfr.us[7] = f2bf_rne(w1.w);
        __syncthreads();
        if (wv < 4) {
            int ntile = wv & 1, cth = wv >> 1;   // wave -> (n-tile, c-half)
            f32x4 acw[KK];
            #pragma unroll
            for (int kk = 0; kk < KK; ++kk) {
                int c = cth*16 + lane15;
                short8 afr = *(const short8*)&kwl[(kk*CC + c)*CC + quad*8];
                acw[kk] = __builtin_amdgcn_mfma_f32_16x16x32_bf16(
                    afr, bfr.s, (f32x4)0.f, 0, 0, 0);
            }
            // D: col(n)=lane15, row(c)=quad*4+reg -> tile[ml>>5][c][ml&31]
            #pragma unroll
            for (int kk = 0; kk < KK; ++kk) {
                int ml = (ntile*16 + lane15)*9 + kk;
                unsigned short* tw = &tile[(ml >> 5)*1024 + (ml & 31)];
                #pragma unroll
                for (int reg = 0; reg < 4; ++reg) {
                    int c = cth*16 + quad*4 + reg;
                    tw[c*32] = f2bf_rne(acw[kk][reg]);
                }
            }
        }
    }
    __syncthreads();
    // writeout: block's 9216-short region contiguous in tiled layout
    {
        short* dst = cwT + (size_t)b*CC*MM + (size_t)nblk*9216;
        #pragma unroll
        for (int it = 0; it < 2; ++it) {
            int u = it*1024 + t;
            if (u < 1152) {
                short8 v = *(const short8*)&tile[u*8];
                *(short8*)&dst[u*8] = v;
            }
        }
    }
    grid_sync(0, 256);

    // ======================= phase B: sample =============================
    {
        int nbase = b*NBB + nblk*32;
        float px[2], py[2];
        #pragma unroll
        for (int nt = 0; nt < 2; ++nt) {
            int n = nbase + nt*16 + lane15;
            px[nt] = SQL2*pos[(size_t)n*2];
            py[nt] = SQL2*pos[(size_t)n*2 + 1];
        }
        f32x4 acc[2][2];
        acc[0][0] = (f32x4)0.f; acc[0][1] = (f32x4)0.f;
        acc[1][0] = (f32x4)0.f; acc[1][1] = (f32x4)0.f;

        const float* qx = qpx + (size_t)b*MM;
        const float* qy = qpy + (size_t)b*MM;
        const short* cab = cwTr + (size_t)b*CC*MM + (size_t)(wv*18)*1024
                         + (size_t)lane15*32 + quad*8;
        const int wvm = wv*576 + quad*8;

        short8 a0A, a1A, a0B, a1B, a0C, a1C;
        f32x4 X0A, X1A, Y0A, Y1A, X0B, X1B, Y0B, Y1B, X0C, X1C, Y0C, Y1C;
        LOADSET(a0A, a1A, X0A, X1A, Y0A, Y1A, 0);
        LOADSET(a0B, a1B, X0B, X1B, Y0B, Y1B, 1);
        LOADSET(a0C, a1C, X0C, X1C, Y0C, Y1C, 2);
        for (int i = 0; i < 6; ++i) {
            int base = i*3;
            COMPUTE(a0A, a1A, X0A, X1A, Y0A, Y1A);
            LOADSET(a0A, a1A, X0A, X1A, Y0A, Y1A, base + 3);
            COMPUTE(a0B, a1B, X0B, X1B, Y0B, Y1B);
            LOADSET(a0B, a1B, X0B, X1B, Y0B, Y1B, base + 4);
            COMPUTE(a0C, a1C, X0C, X1C, Y0C, Y1C);
            LOADSET(a0C, a1C, X0C, X1C, Y0C, Y1C, base + 5);
        }
        // per-wave partials -> LDS red[wv][nloc][c]
        #pragma unroll
        for (int nt = 0; nt < 2; ++nt)
            #pragma unroll
            for (int ct = 0; ct < 2; ++ct) {
                int nn = nt*16 + lane15, c = ct*16 + quad*4;
                *(f32x4*)&red[(wv*32 + nn)*36 + c] = acc[nt][ct];
            }
        __syncthreads();
        // reduce 16 partials, leaky, x0 -> global, s1 stats
        if (t < 256) {
            int nr = t >> 3, c0 = (t & 7)*4;
            f32x4 v = (f32x4)0.f;
            #pragma unroll
            for (int wp = 0; wp < 16; ++wp)
                v = v + *(const f32x4*)&red[(wp*32 + nr)*36 + c0];
            v.x = v.x >= 0.f ? v.x : NEG*v.x;
            v.y = v.y >= 0.f ? v.y : NEG*v.y;
            v.z = v.z >= 0.f ? v.z : NEG*v.z;
            v.w = v.w >= 0.f ? v.w : NEG*v.w;
            *(f32x4*)&x0[((size_t)(nbase + nr))*CC + c0] = v;
            float s0 = v.x, s1v = v.y, s2v = v.z, s3v = v.w;
            float q0 = v.x*v.x, q1 = v.y*v.y, q2 = v.z*v.z, q3 = v.w*v.w;
            #pragma unroll
            for (int mk = 8; mk <= 32; mk <<= 1) {
                s0 += __shfl_xor(s0, mk); s1v += __shfl_xor(s1v, mk);
                s2v += __shfl_xor(s2v, mk); s3v += __shfl_xor(s3v, mk);
                q0 += __shfl_xor(q0, mk); q1 += __shfl_xor(q1, mk);
                q2 += __shfl_xor(q2, mk); q3 += __shfl_xor(q3, mk);
            }
            if (l < 8) {
                atomicAdd(&sstat[c0 + 0], s0);  atomicAdd(&sstat[c0 + 1], s1v);
                atomicAdd(&sstat[c0 + 2], s2v); atomicAdd(&sstat[c0 + 3], s3v);
                atomicAdd(&sstat[32 + c0 + 0], q0); atomicAdd(&sstat[32 + c0 + 1], q1);
                atomicAdd(&sstat[32 + c0 + 2], q2); atomicAdd(&sstat[32 + c0 + 3], q3);
            }
        }
        __syncthreads();
        if (t < 64) atomicAdd(&stats[t], sstat[t]);
    }
}

// ---------------------------------------------------------------------------
// k_mlp: mlp1 then mlp2, fused with ONE grid barrier.
// grid = 512 x 256 (2 blocks/CU — 512 co-resident guaranteed: LDS 35.8KB,
// small VGPR). Phase 1 = r7 k_mlp1 (64 n x 32 j-quarter); barrier;
// phase 2 = r7 k_mlp2 (16 n, 16 rid-slices).
// ---------------------------------------------------------------------------
__global__ __launch_bounds__(256) void k_mlp(const float* __restrict__ x0,
                                             const float* __restrict__ wts,
                                             const float* __restrict__ gma,
                                             const float* __restrict__ bta,
                                             const float* __restrict__ W1,
                                             const float* __restrict__ b1,
                                             const float* __restrict__ s1,
                                             float* __restrict__ x,
                                             float* __restrict__ h0,
                                             float* __restrict__ s2,
                                             const float* __restrict__ pos,
                                             const float* __restrict__ g2,
                                             const float* __restrict__ bt2,
                                             const float* __restrict__ W2,
                                             const float* __restrict__ b2,
                                             float* __restrict__ out) {
    __shared__ float sm[16*16*35];   // 35.8 KB (phase2); phase1 uses 8.7 KB
    int t = threadIdx.x;
    int l = t & 63, wv = t >> 6;
    int blk = blockIdx.x;

    // ======================= phase 1: bn1 + mlp1 + s2 ====================
    {
        float* tile = sm;            // [j_local][n] padded [32][68]
        int nb = blk >> 2, jq = blk & 3;
        int n = nb*64 + l;
        int j0 = jq*32 + wv*8;

        float xv[32];
        #pragma unroll
        for (int c = 0; c < 32; ++c) {
            float mu  = s1[c] * (1.f/NTOT);
            float var = s1[32+c]*(1.f/NTOT) - mu*mu;
            float a   = gma[c] * rsqrtf(var + EPS);
            float v   = x0[(size_t)n*CC + c];
            xv[c] = a*(v - mu) + bta[c] + wts[(size_t)n*CC + c];
        }
        if (jq == 0 && wv == 0) {
            #pragma unroll
            for (int c = 0; c < 32; c += 4)
                *(float4*)&x[(size_t)n*CC + c] = make_float4(xv[c], xv[c+1], xv[c+2], xv[c+3]);
        }
        float acc[8];
        *(f32x4*)&acc[0] = *(const f32x4*)&b1[j0];
        *(f32x4*)&acc[4] = *(const f32x4*)&b1[j0 + 4];
        #pragma unroll 8
        for (int c = 0; c < 32; ++c) {
            float xc = xv[c];
            const float* w1r = W1 + c*CMM + j0;   // wave-uniform -> s_load
            f32x4 wa = *(const f32x4*)&w1r[0];
            f32x4 wb = *(const f32x4*)&w1r[4];
            acc[0] = fmaf(xc, wa.x, acc[0]); acc[1] = fmaf(xc, wa.y, acc[1]);
            acc[2] = fmaf(xc, wa.z, acc[2]); acc[3] = fmaf(xc, wa.w, acc[3]);
            acc[4] = fmaf(xc, wb.x, acc[4]); acc[5] = fmaf(xc, wb.y, acc[5]);
            acc[6] = fmaf(xc, wb.z, acc[6]); acc[7] = fmaf(xc, wb.w, acc[7]);
        }
        #pragma unroll
        for (int jj = 0; jj < 8; ++jj) {
            acc[jj] = acc[jj] >= 0.f ? acc[jj] : NEG*acc[jj];
            tile[(wv*8 + jj)*68 + l] = acc[jj];
        }
        float* hd = h0 + (size_t)n*CMM + j0;
        *(float4*)&hd[0] = make_float4(acc[0], acc[1], acc[2], acc[3]);
        *(float4*)&hd[4] = make_float4(acc[4], acc[5], acc[6], acc[7]);
        __syncthreads();
        // stats: thread -> (j_local = t>>3, grp = t&7), 8 n each
        {
            int jl = t >> 3, grp = t & 7;
            float lsum = 0.f, lsq = 0.f;
            #pragma unroll
            for (int q = 0; q < 2; ++q) {
                f32x4 v = *(const f32x4*)&tile[jl*68 + grp*8 + q*4];
                lsum += v.x + v.y + v.z + v.w;
                lsq = fmaf(v.x, v.x, fmaf(v.y, v.y, fmaf(v.z, v.z, fmaf(v.w, v.w, lsq))));
            }
            lsum += __shfl_xor(lsum, 1); lsq += __shfl_xor(lsq, 1);
            lsum += __shfl_xor(lsum, 2); lsq += __shfl_xor(lsq, 2);
            lsum += __shfl_xor(lsum, 4); lsq += __shfl_xor(lsq, 4);
            if (grp == 0) {
                int jg = jq*32 + jl;
                atomicAdd(&s2[jg], lsum);
                atomicAdd(&s2[CMM + jg], lsq);
            }
        }
    }
    grid_sync(1, 512);

    // ======================= phase 2: bn2 + mlp2 + out ===================
    {
        float* red = sm;             // [rid][n][c] = [16][16][35]
        int nl = t & 15, rid = t >> 4;
        int n = blk*16 + nl;
        int j0 = rid*8;
        float hv[8];
        *(f32x4*)&hv[0] = *(const f32x4*)&h0[(size_t)n*CMM + j0];
        *(f32x4*)&hv[4] = *(const f32x4*)&h0[(size_t)n*CMM + j0 + 4];
        #pragma unroll
        for (int jj = 0; jj < 8; ++jj) {
            int j = j0 + jj;
            float mu  = s2[j] * (1.f/NTOT);
            float var = s2[CMM+j]*(1.f/NTOT) - mu*mu;
            float a   = g2[j] * rsqrtf(var + EPS);
            hv[jj] = a*(hv[jj] - mu) + bt2[j];
        }
        float acc[34];
        #pragma unroll
        for (int c = 0; c < 34; ++c) acc[c] = 0.f;
        for (int jj = 0; jj < 8; ++jj) {
            float h = hv[jj];
            const float* w2r = W2 + (size_t)(j0 + jj)*34;
            #pragma unroll
            for (int c = 0; c < 34; ++c)
                acc[c] = fmaf(h, w2r[c], acc[c]);
        }
        #pragma unroll
        for (int c = 0; c < 34; ++c) red[(rid*16 + nl)*35 + c] = acc[c];
        __syncthreads();
        // 16 n x 34 c = 544 outputs over 256 threads
        #pragma unroll
        for (int it = 0; it < 3; ++it) {
            int u = it*256 + t;
            if (u < 544) {
                int r = u / 34, c = u - r*34;
                float v = b2[c];
                #pragma unroll
                for (int rr = 0; rr < 16; ++rr) v += red[(rr*16 + r)*35 + c];
                int nn = blk*16 + r;
                if (c < 2)
                    out[(size_t)nn*2 + c] = pos[(size_t)nn*2 + c] + v;
                else
                    out[16384 + (size_t)nn*32 + (c-2)] = x[(size_t)nn*32 + (c-2)] + v;
            }
        }
    }
}

// ---------------------------------------------------------------------------
extern "C" void kernel_launch(void* const* d_in, const int* in_sizes, int n_in,
                              void* d_out, int out_size, void* d_ws, size_t ws_size,
                              hipStream_t stream) {
    const float* positions = (const float*)d_in[0];
    const float* weights   = (const float*)d_in[1];
    // d_in[2] = batch (int32) — unused, shapes static
    const float* kpos = (const float*)d_in[3];
    const float* kw   = (const float*)d_in[4];
    const float* cg   = (const float*)d_in[5];
    const float* cb   = (const float*)d_in[6];
    const float* W1   = (const float*)d_in[7];
    const float* b1   = (const float*)d_in[8];
    const float* bg   = (const float*)d_in[9];
    const float* bb   = (const float*)d_in[10];
    const float* W2   = (const float*)d_in[11];
    const float* b2   = (const float*)d_in[12];
    float* ws  = (float*)d_ws;
    float* out = (float*)d_out;

    float* s1 = ws + OFF_ST;        // 64 floats
    float* s2 = ws + OFF_ST + 64;   // 256 floats

    k_cs<<<256, 1024, 0, stream>>>(positions, kpos, weights, kw,
                                   ws + OFF_QPX, ws + OFF_QPY,
                                   (const short*)(ws + OFF_CWT),
                                   (short*)(ws + OFF_CWT),
                                   ws + OFF_X0, s1);
    k_mlp<<<512, 256, 0, stream>>>(ws + OFF_X0, weights, cg, cb, W1, b1,
                                   s1, ws + OFF_X, ws + OFF_H0, s2,
                                   positions, bg, bb, W2, b2, out);
}

// Round 9
// 142.602 us; speedup vs baseline: 3.0628x; 3.0628x over previous
//
#include <hip/hip_runtime.h>
#include <hip/hip_bf16.h>

// Problem constants
#define BB    8
#define NBB   1024
#define KK    9
#define CC    32
#define CMM   128
#define NTOT  (BB*NBB)        // 8192
#define MM    (NBB*KK)        // 9216 per batch
#define NEG   0.01f
#define EPS   1e-5f
#define SQL2  1.6986436f      /* sqrt(2*log2(e)); E = -((s*dx)^2 + (s*dy)^2) */

// Workspace layout (floats)
#define OFF_CWT   0
#define SZ_CWT    (BB*CC*MM/2)            // bf16 in float-slots: 1179648
#define OFF_QPX   (OFF_CWT + SZ_CWT)
#define OFF_QPY   (OFF_QPX + BB*MM)
#define OFF_X0    (OFF_QPY + BB*MM)
#define OFF_X     (OFF_X0 + NTOT*CC)
#define OFF_H0    (OFF_X + NTOT*CC)
#define OFF_ST    (OFF_H0 + NTOT*CMM)     // stats: s1[64] then s2[256]

typedef __attribute__((ext_vector_type(8))) short short8;
typedef __attribute__((ext_vector_type(4))) float f32x4;
typedef __attribute__((ext_vector_type(2))) float f32x2;

static __device__ __forceinline__ unsigned short f2bf_rne(float f) {
    __hip_bfloat16 h = __float2bfloat16(f);
    return *reinterpret_cast<unsigned short*>(&h);
}

// ---------------------------------------------------------------------------
// cwT layout: A-fragment tiles. Element (b, m, c) lives at short offset
//   b*CC*MM + (m>>5)*1024 + c*32 + (m&31)
// -> a wave's MFMA A-frag load is a contiguous 2 KB block (coalesced).
// ---------------------------------------------------------------------------

// ---------------------------------------------------------------------------
// k_convw (MFMA) + folded prep. grid = 256 (b = blk&7 -> XCD-aligned batch),
// 32 n per block (9 m-chunks of 32). ALL 4 waves do MFMA:
// wave wv -> (ntile = wv&1, c-half = wv>>1), 9 MFMA each.
// ---------------------------------------------------------------------------
__global__ __launch_bounds__(256) void k_convw(const float* __restrict__ pos,
                                               const float* __restrict__ kpos,
                                               const float* __restrict__ w,
                                               const float* __restrict__ kw,
                                               float* __restrict__ qpx,
                                               float* __restrict__ qpy,
                                               float* __restrict__ stats,
                                               short* __restrict__ cwT) {
    __shared__ unsigned short kwl[KK*CC*CC];   // 18 KB  kwT bf16 [k][c][cp]
    __shared__ unsigned short tile[9*32*32];   // 18 KB  [mchunk][c][m%32]
    int t = threadIdx.x;
    int l = t & 63, wv = t >> 6;
    int lane15 = l & 15, quad = l >> 4;
    int blk = blockIdx.x;
    int b = blk & 7, nbl = blk >> 3;           // nbl in [0,32): 32-n tile

    // ---- folded prep: 73728 items over 65536 threads (2 reps) ----
    if (blk == 0 && t < 320) stats[t] = 0.f;
    #pragma unroll
    for (int rep = 0; rep < 2; ++rep) {
        int gid = rep*65536 + blk*256 + t;
        if (gid < BB*MM) {
            int bb = gid / MM;
            int m = gid - bb*MM;
            int np = m / 9, k9 = m - np*9;
            float qx = pos[((size_t)(bb*NBB + np))*2 + 0] + kpos[k9*2 + 0];
            float qy = pos[((size_t)(bb*NBB + np))*2 + 1] + kpos[k9*2 + 1];
            qpx[gid] = SQL2*qx;
            qpy[gid] = SQL2*qy;
        }
    }
    // ---- stage kw -> LDS bf16 transposed [k][c][cp] ----
    for (int u = t; u < KK*CC*CC/4; u += 256) {
        int flat = u*4;
        int row = flat >> 5;
        int c0 = flat & 31;
        int kk = row >> 5, cp = row & 31;
        f32x4 v = *(const f32x4*)&kw[flat];
        kwl[(kk*CC + c0+0)*CC + cp] = f2bf_rne(v.x);
        kwl[(kk*CC + c0+1)*CC + cp] = f2bf_rne(v.y);
        kwl[(kk*CC + c0+2)*CC + cp] = f2bf_rne(v.z);
        kwl[(kk*CC + c0+3)*CC + cp] = f2bf_rne(v.w);
    }
    // B-frag: w[n][quad*8 .. +7] -> bf16; wave's n-tile = wv&1
    int n = b*NBB + nbl*32 + (wv & 1)*16 + lane15;
    f32x4 w0 = *(const f32x4*)&w[(size_t)n*CC + quad*8];
    f32x4 w1 = *(const f32x4*)&w[(size_t)n*CC + quad*8 + 4];
    union { unsigned short us[8]; short8 s; } bfr;
    bfr.us[0] = f2bf_rne(w0.x); bfr.us[1] = f2bf_rne(w0.y);
    bfr.us[2] = f2bf_rne(w0.z); bfr.us[3] = f2bf_rne(w0.w);
    bfr.us[4] = f2bf_rne(w1.x); bfr.us[5] = f2bf_rne(w1.y);
    bfr.us[6] = f2bf_rne(w1.z); bfr.us[7] = f2bf_rne(w1.w);
    __syncthreads();
    {
        int ntile = wv & 1, cth = wv >> 1;     // wave -> (n-tile, c-half)
        f32x4 acc[KK];
        #pragma unroll
        for (int kk = 0; kk < KK; ++kk) {
            int c = cth*16 + lane15;
            short8 afr = *(const short8*)&kwl[(kk*CC + c)*CC + quad*8];
            acc[kk] = __builtin_amdgcn_mfma_f32_16x16x32_bf16(
                afr, bfr.s, (f32x4)0.f, 0, 0, 0);
        }
        // D: col(n)=lane15, row(c)=quad*4+reg.
        // ml = (ntile*16 + lane15)*9 + kk -> tile[ml>>5][c][ml&31]
        #pragma unroll
        for (int kk = 0; kk < KK; ++kk) {
            int ml = (ntile*16 + lane15)*9 + kk;
            unsigned short* tw = &tile[(ml >> 5)*1024 + (ml & 31)];
            #pragma unroll
            for (int reg = 0; reg < 4; ++reg) {
                int c = cth*16 + quad*4 + reg;
                tw[c*32] = f2bf_rne(acc[kk][reg]);
            }
        }
    }
    __syncthreads();
    // writeout: block's 9216-short region is CONTIGUOUS in the tiled layout
    short* dst = cwT + (size_t)b*CC*MM + (size_t)nbl*9216;
    #pragma unroll
    for (int it = 0; it < 5; ++it) {
        int u = it*256 + t;
        if (u < 1152) {
            short8 v = *(const short8*)&tile[u*8];
            *(short8*)&dst[u*8] = v;
        }
    }
}

// ---------------------------------------------------------------------------
// k_sample (dominant, MFMA) + in-block reduce + leaky + s1 stats.
// grid = 256 blocks x 1024 threads (16 waves, 4 waves/SIMD, 1 block/CU).
// 32 n per block (2 n-tiles), 16-way m-split (576 m/wave, 18 iters).
// 1-deep load pipeline (r6 champion form). Tiled cwT A-loads: contiguous 2KB.
// ---------------------------------------------------------------------------
__global__ __launch_bounds__(1024, 4) void k_sample(const float* __restrict__ pos,
                                                    const float* __restrict__ qpx,
                                                    const float* __restrict__ qpy,
                                                    const short* __restrict__ cwT,
                                                    float* __restrict__ x0,
                                                    float* __restrict__ s1) {
    __shared__ float red[16*32*36];   // 72 KB: [wv][nloc][c] pad 36
    __shared__ float sstat[64];
    int t = threadIdx.x;
    int l = t & 63, wv = t >> 6;
    int blk = blockIdx.x;
    int b = blk & 7, nblk = blk >> 3;
    int lane15 = l & 15, quad = l >> 4;
    int nbase = b*NBB + nblk*32;
    if (t < 64) sstat[t] = 0.f;

    float px[2], py[2];
    #pragma unroll
    for (int nt = 0; nt < 2; ++nt) {
        int n = nbase + nt*16 + lane15;
        px[nt] = SQL2*pos[(size_t)n*2];
        py[nt] = SQL2*pos[(size_t)n*2 + 1];
    }
    f32x4 acc[2][2];
    acc[0][0] = (f32x4)0.f; acc[0][1] = (f32x4)0.f;
    acc[1][0] = (f32x4)0.f; acc[1][1] = (f32x4)0.f;

    const float* qx = qpx + (size_t)b*MM;
    const float* qy = qpy + (size_t)b*MM;
    // tiled A: a0 at chunk*1024 + lane15*32 + quad*8 ; a1 at +512 (c+16)
    const short* cab = cwT + (size_t)b*CC*MM + (size_t)lane15*32 + quad*8;

    int m0 = wv*576 + quad*8;              // coefficient index
    int ma = (wv*18) * 1024;               // tile offset for this wave's chunks
    // prologue loads
    short8 a0 = *(const short8*)&cab[ma];
    short8 a1 = *(const short8*)&cab[ma + 512];
    f32x4 X0 = *(const f32x4*)&qx[m0], X1 = *(const f32x4*)&qx[m0 + 4];
    f32x4 Y0 = *(const f32x4*)&qy[m0], Y1 = *(const f32x4*)&qy[m0 + 4];
    for (int kk = 0; kk < 18; ++kk) {
        int step = (kk < 17) ? 1 : 0;
        int mn = m0 + step*32;
        int man = ma + step*1024;
        // issue next-iteration loads BEFORE compute (1-deep pipeline)
        short8 na0 = *(const short8*)&cab[man];
        short8 na1 = *(const short8*)&cab[man + 512];
        f32x4 nX0 = *(const f32x4*)&qx[mn], nX1 = *(const f32x4*)&qx[mn + 4];
        f32x4 nY0 = *(const f32x4*)&qy[mn], nY1 = *(const f32x4*)&qy[mn + 4];
        #pragma unroll
        for (int nt = 0; nt < 2; ++nt) {
            f32x2 PX = {px[nt], px[nt]};
            f32x2 PY = {py[nt], py[nt]};
            f32x2 dx0 = (f32x2){X0.x, X0.y} - PX;
            f32x2 dy0 = (f32x2){Y0.x, Y0.y} - PY;
            f32x2 t0 = dx0*dx0; t0 = dy0*dy0 + t0;
            f32x2 dx1 = (f32x2){X0.z, X0.w} - PX;
            f32x2 dy1 = (f32x2){Y0.z, Y0.w} - PY;
            f32x2 t1 = dx1*dx1; t1 = dy1*dy1 + t1;
            f32x2 dx2 = (f32x2){X1.x, X1.y} - PX;
            f32x2 dy2 = (f32x2){Y1.x, Y1.y} - PY;
            f32x2 t2 = dx2*dx2; t2 = dy2*dy2 + t2;
            f32x2 dx3 = (f32x2){X1.z, X1.w} - PX;
            f32x2 dy3 = (f32x2){Y1.z, Y1.w} - PY;
            f32x2 t3 = dx3*dx3; t3 = dy3*dy3 + t3;
            float e0 = __builtin_amdgcn_exp2f(-t0.x);
            float e1 = __builtin_amdgcn_exp2f(-t0.y);
            float e2 = __builtin_amdgcn_exp2f(-t1.x);
            float e3 = __builtin_amdgcn_exp2f(-t1.y);
            float e4 = __builtin_amdgcn_exp2f(-t2.x);
            float e5 = __builtin_amdgcn_exp2f(-t2.y);
            float e6 = __builtin_amdgcn_exp2f(-t3.x);
            float e7 = __builtin_amdgcn_exp2f(-t3.y);
            union { unsigned int u[4]; short8 s; } bf;
            bf.u[0] = (__float_as_uint(e0) >> 16) | (__float_as_uint(e1) & 0xffff0000u);
            bf.u[1] = (__float_as_uint(e2) >> 16) | (__float_as_uint(e3) & 0xffff0000u);
            bf.u[2] = (__float_as_uint(e4) >> 16) | (__float_as_uint(e5) & 0xffff0000u);
            bf.u[3] = (__float_as_uint(e6) >> 16) | (__float_as_uint(e7) & 0xffff0000u);
            acc[nt][0] = __builtin_amdgcn_mfma_f32_16x16x32_bf16(a0, bf.s, acc[nt][0], 0, 0, 0);
            acc[nt][1] = __builtin_amdgcn_mfma_f32_16x16x32_bf16(a1, bf.s, acc[nt][1], 0, 0, 0);
        }
        a0 = na0; a1 = na1;
        X0 = nX0; X1 = nX1; Y0 = nY0; Y1 = nY1;
        m0 = mn; ma = man;
    }
    // per-wave partials -> LDS red[wv][nloc][c] (D: col(n)=lane15, row(c)=quad*4+reg)
    #pragma unroll
    for (int nt = 0; nt < 2; ++nt)
        #pragma unroll
        for (int ct = 0; ct < 2; ++ct) {
            int nn = nt*16 + lane15, c = ct*16 + quad*4;
            *(f32x4*)&red[(wv*32 + nn)*36 + c] = acc[nt][ct];
        }
    __syncthreads();
    // reduce 16 partials, leaky, x0 -> global, s1 stats (threads 0..255)
    if (t < 256) {
        int nr = t >> 3, c0 = (t & 7)*4;
        f32x4 v = (f32x4)0.f;
        #pragma unroll
        for (int wp = 0; wp < 16; ++wp)
            v = v + *(const f32x4*)&red[(wp*32 + nr)*36 + c0];
        v.x = v.x >= 0.f ? v.x : NEG*v.x;
        v.y = v.y >= 0.f ? v.y : NEG*v.y;
        v.z = v.z >= 0.f ? v.z : NEG*v.z;
        v.w = v.w >= 0.f ? v.w : NEG*v.w;
        *(f32x4*)&x0[((size_t)(nbase + nr))*CC + c0] = v;
        float s0 = v.x, s1v = v.y, s2v = v.z, s3v = v.w;
        float q0 = v.x*v.x, q1 = v.y*v.y, q2 = v.z*v.z, q3 = v.w*v.w;
        #pragma unroll
        for (int mk = 8; mk <= 32; mk <<= 1) {
            s0 += __shfl_xor(s0, mk); s1v += __shfl_xor(s1v, mk);
            s2v += __shfl_xor(s2v, mk); s3v += __shfl_xor(s3v, mk);
            q0 += __shfl_xor(q0, mk); q1 += __shfl_xor(q1, mk);
            q2 += __shfl_xor(q2, mk); q3 += __shfl_xor(q3, mk);
        }
        if (l < 8) {
            atomicAdd(&sstat[c0 + 0], s0);  atomicAdd(&sstat[c0 + 1], s1v);
            atomicAdd(&sstat[c0 + 2], s2v); atomicAdd(&sstat[c0 + 3], s3v);
            atomicAdd(&sstat[32 + c0 + 0], q0); atomicAdd(&sstat[32 + c0 + 1], q1);
            atomicAdd(&sstat[32 + c0 + 2], q2); atomicAdd(&sstat[32 + c0 + 3], q3);
        }
    }
    __syncthreads();
    if (t < 64) atomicAdd(&s1[t], sstat[t]);   // 64 global atomics per block
}

// ---------------------------------------------------------------------------
// k_mlp1: x = bn1(x0) + weights; h0 = leaky(x @ W1 + b1); fused bn2 stats.
// grid = 512: block = 64 n x 32 j (j-quarter). 2 blocks/CU, 2 waves/SIMD.
// ---------------------------------------------------------------------------
__global__ __launch_bounds__(256) void k_mlp1(const float* __restrict__ x0,
                                              const float* __restrict__ wts,
                                              const float* __restrict__ gma,
                                              const float* __restrict__ bta,
                                              const float* __restrict__ W1,
                                              const float* __restrict__ b1,
                                              const float* __restrict__ s1,
                                              float* __restrict__ x,
                                              float* __restrict__ h0,
                                              float* __restrict__ s2) {
    __shared__ float tile[32*68];   // [j_local][n] padded
    int t = threadIdx.x;
    int l = t & 63, wv = t >> 6;
    int blk = blockIdx.x;
    int nb = blk >> 2, jq = blk & 3;
    int n = nb*64 + l;
    int j0 = jq*32 + wv*8;

    float xv[32];
    #pragma unroll
    for (int c = 0; c < 32; ++c) {
        float mu  = s1[c] * (1.f/NTOT);
        float var = s1[32+c]*(1.f/NTOT) - mu*mu;
        float a   = gma[c] * rsqrtf(var + EPS);
        float v   = x0[(size_t)n*CC + c];
        xv[c] = a*(v - mu) + bta[c] + wts[(size_t)n*CC + c];
    }
    if (jq == 0 && wv == 0) {
        #pragma unroll
        for (int c = 0; c < 32; c += 4)
            *(float4*)&x[(size_t)n*CC + c] = make_float4(xv[c], xv[c+1], xv[c+2], xv[c+3]);
    }
    float acc[8];
    *(f32x4*)&acc[0] = *(const f32x4*)&b1[j0];
    *(f32x4*)&acc[4] = *(const f32x4*)&b1[j0 + 4];
    #pragma unroll 8
    for (int c = 0; c < 32; ++c) {
        float xc = xv[c];
        const float* w1r = W1 + c*CMM + j0;   // wave-uniform -> s_load
        f32x4 wa = *(const f32x4*)&w1r[0];
        f32x4 wb = *(const f32x4*)&w1r[4];
        acc[0] = fmaf(xc, wa.x, acc[0]); acc[1] = fmaf(xc, wa.y, acc[1]);
        acc[2] = fmaf(xc, wa.z, acc[2]); acc[3] = fmaf(xc, wa.w, acc[3]);
        acc[4] = fmaf(xc, wb.x, acc[4]); acc[5] = fmaf(xc, wb.y, acc[5]);
        acc[6] = fmaf(xc, wb.z, acc[6]); acc[7] = fmaf(xc, wb.w, acc[7]);
    }
    #pragma unroll
    for (int jj = 0; jj < 8; ++jj) {
        acc[jj] = acc[jj] >= 0.f ? acc[jj] : NEG*acc[jj];
        tile[(wv*8 + jj)*68 + l] = acc[jj];
    }
    float* hd = h0 + (size_t)n*CMM + j0;
    *(float4*)&hd[0] = make_float4(acc[0], acc[1], acc[2], acc[3]);
    *(float4*)&hd[4] = make_float4(acc[4], acc[5], acc[6], acc[7]);
    __syncthreads();
    // stats: thread -> (j_local = t>>3, grp = t&7), 8 n each
    if (t < 256) {
        int jl = t >> 3, grp = t & 7;
        float lsum = 0.f, lsq = 0.f;
        #pragma unroll
        for (int q = 0; q < 2; ++q) {
            f32x4 v = *(const f32x4*)&tile[jl*68 + grp*8 + q*4];
            lsum += v.x + v.y + v.z + v.w;
            lsq = fmaf(v.x, v.x, fmaf(v.y, v.y, fmaf(v.z, v.z, fmaf(v.w, v.w, lsq))));
        }
        lsum += __shfl_xor(lsum, 1); lsq += __shfl_xor(lsq, 1);
        lsum += __shfl_xor(lsum, 2); lsq += __shfl_xor(lsq, 2);
        lsum += __shfl_xor(lsum, 4); lsq += __shfl_xor(lsq, 4);
        if (grp == 0) {
            int jg = jq*32 + jl;
            atomicAdd(&s2[jg], lsum);
            atomicAdd(&s2[CMM + jg], lsq);
        }
    }
}

// ---------------------------------------------------------------------------
// k_mlp2: h = bn2(h0); mlp = h @ W2 + b2; out0 = pos + mlp[:,:2];
//         out1 = x + mlp[:,2:]
// grid = 512: 16 n per block, 16 rid-slices of 8 j, 16-way LDS reduce.
// ---------------------------------------------------------------------------
__global__ __launch_bounds__(256) void k_mlp2(const float* __restrict__ h0,
                                              const float* __restrict__ x,
                                              const float* __restrict__ pos,
                                              const float* __restrict__ g2,
                                              const float* __restrict__ bt2,
                                              const float* __restrict__ W2,
                                              const float* __restrict__ b2,
                                              const float* __restrict__ s2,
                                              float* __restrict__ out) {
    __shared__ float red[16*16*35];   // 35 KB: [rid][n][c]
    int t = threadIdx.x;
    int nl = t & 15, rid = t >> 4;    // rid in [0,16)
    int n = blockIdx.x*16 + nl;
    int j0 = rid*8;
    float hv[8];
    *(f32x4*)&hv[0] = *(const f32x4*)&h0[(size_t)n*CMM + j0];
    *(f32x4*)&hv[4] = *(const f32x4*)&h0[(size_t)n*CMM + j0 + 4];
    #pragma unroll
    for (int jj = 0; jj < 8; ++jj) {
        int j = j0 + jj;
        float mu  = s2[j] * (1.f/NTOT);
        float var = s2[CMM+j]*(1.f/NTOT) - mu*mu;
        float a   = g2[j] * rsqrtf(var + EPS);
        hv[jj] = a*(hv[jj] - mu) + bt2[j];
    }
    float acc[34];
    #pragma unroll
    for (int c = 0; c < 34; ++c) acc[c] = 0.f;
    for (int jj = 0; jj < 8; ++jj) {
        float h = hv[jj];
        const float* w2r = W2 + (size_t)(j0 + jj)*34;
        #pragma unroll
        for (int c = 0; c < 34; ++c)
            acc[c] = fmaf(h, w2r[c], acc[c]);
    }
    #pragma unroll
    for (int c = 0; c < 34; ++c) red[(rid*16 + nl)*35 + c] = acc[c];
    __syncthreads();
    // 16 n x 34 c = 544 outputs over 256 threads
    #pragma unroll
    for (int it = 0; it < 3; ++it) {
        int u = it*256 + t;
        if (u < 544) {
            int r = u / 34, c = u - r*34;
            float v = b2[c];
            #pragma unroll
            for (int rr = 0; rr < 16; ++rr) v += red[(rr*16 + r)*35 + c];
            int nn = blockIdx.x*16 + r;
            if (c < 2)
                out[(size_t)nn*2 + c] = pos[(size_t)nn*2 + c] + v;
            else
                out[16384 + (size_t)nn*32 + (c-2)] = x[(size_t)nn*32 + (c-2)] + v;
        }
    }
}

// ---------------------------------------------------------------------------
extern "C" void kernel_launch(void* const* d_in, const int* in_sizes, int n_in,
                              void* d_out, int out_size, void* d_ws, size_t ws_size,
                              hipStream_t stream) {
    const float* positions = (const float*)d_in[0];
    const float* weights   = (const float*)d_in[1];
    // d_in[2] = batch (int32) — unused, shapes static
    const float* kpos = (const float*)d_in[3];
    const float* kw   = (const float*)d_in[4];
    const float* cg   = (const float*)d_in[5];
    const float* cb   = (const float*)d_in[6];
    const float* W1   = (const float*)d_in[7];
    const float* b1   = (const float*)d_in[8];
    const float* bg   = (const float*)d_in[9];
    const float* bb   = (const float*)d_in[10];
    const float* W2   = (const float*)d_in[11];
    const float* b2   = (const float*)d_in[12];
    float* ws  = (float*)d_ws;
    float* out = (float*)d_out;

    float* s1 = ws + OFF_ST;        // 64 floats
    float* s2 = ws + OFF_ST + 64;   // 256 floats

    k_convw<<<256, 256, 0, stream>>>(positions, kpos, weights, kw,
                                     ws + OFF_QPX, ws + OFF_QPY,
                                     s1, (short*)(ws + OFF_CWT));
    k_sample<<<256, 1024, 0, stream>>>(positions, ws + OFF_QPX, ws + OFF_QPY,
                                       (const short*)(ws + OFF_CWT),
                                       ws + OFF_X0, s1);
    k_mlp1<<<512, 256, 0, stream>>>(ws + OFF_X0, weights, cg, cb, W1, b1,
                                    s1, ws + OFF_X, ws + OFF_H0, s2);
    k_mlp2<<<512, 256, 0, stream>>>(ws + OFF_H0, ws + OFF_X, positions,
                                    bg, bb, W2, b2, s2, out);
}